// Round 3
// baseline (59.919 us; speedup 1.0000x reference)
//
#include <hip/hip_runtime.h>
#include <hip/hip_bf16.h>

typedef __attribute__((ext_vector_type(8))) short short8;
typedef __attribute__((ext_vector_type(4))) float floatx4;

#define B_ROWS 8192
#define DIM 128
#define NPAIR 4095

// ---------------- zero Z (fallback path only) ----------------
__global__ void kzero(float* __restrict__ Z) {
    int i = blockIdx.x * 256 + threadIdx.x;
    if (i < B_ROWS) Z[i] = 0.f;
}

// ------------- fused prep: normalize rows -> bf16, pair dots, zero out -------------
// block = 256 threads = 4 waves = 4 rows; pairs (2b, 2b+1) live inside block b.
__global__ void kprep(const float* __restrict__ X, __hip_bfloat16* __restrict__ XN,
                      float* __restrict__ pairT, float* __restrict__ out) {
    __shared__ float2 lds[4][64];
    const int wid = threadIdx.x >> 6;
    const int lane = threadIdx.x & 63;
    const int row = blockIdx.x * 4 + wid;

    const float2 v = *reinterpret_cast<const float2*>(X + row * DIM + lane * 2);
    float ss = v.x * v.x + v.y * v.y;
    #pragma unroll
    for (int m = 1; m < 64; m <<= 1) ss += __shfl_xor(ss, m, 64);
    const float rn = ss > 0.f ? rsqrtf(ss) : 0.f;
    const float2 nv = make_float2(v.x * rn, v.y * rn);

    *reinterpret_cast<__hip_bfloat162*>(XN + row * DIM + lane * 2) =
        __float22bfloat162_rn(nv);
    lds[wid][lane] = nv;
    __syncthreads();

    // waves 0 and 2 compute the two pair similarities (fp32, normalized rows)
    if ((wid & 1) == 0) {
        const int p = blockIdx.x * 2 + (wid >> 1);
        if (p < NPAIR) {
            const float2 a = lds[wid][lane];
            const float2 b = lds[wid + 1][lane];
            float d = a.x * b.x + a.y * b.y;
            #pragma unroll
            for (int m = 1; m < 64; m <<= 1) d += __shfl_xor(d, m, 64);
            if (lane == 0) pairT[p] = d;
        }
    }
    if (blockIdx.x == 0 && threadIdx.x == 0) out[0] = 0.f;
}

// ------------- main: upper-triangle S tiles, fragments direct from L2 -------------
// grid = 2080 triangle tiles, block 256 = 4 waves, no LDS, no barriers.
// Each fragment load = 16 rows x 64B cache lines, fully utilized.
template <bool USEP>
__global__ void __launch_bounds__(256) kgemm(const __hip_bfloat16* __restrict__ XN,
                                             float* __restrict__ ZP) {
    const int tid = threadIdx.x;
    const int wid = tid >> 6;
    const int lane = tid & 63;
    const int lr = lane & 15;
    const int lk = lane >> 4;

    // triangular decode blockIdx.x -> (rb <= cb)
    const int t = blockIdx.x;
    int cb = (int)((sqrtf(8.f * (float)t + 1.f) - 1.f) * 0.5f);
    while ((cb + 1) * (cb + 2) / 2 <= t) ++cb;
    while (cb * (cb + 1) / 2 > t) --cb;
    const int rb = t - cb * (cb + 1) / 2;
    const bool diag = (rb == cb);

    const int wr = wid >> 1;  // wave row quadrant (64 rows)
    const int wc = wid & 1;   // wave col quadrant (64 cols)

    const __hip_bfloat16* Abase = XN + (rb * 128 + wr * 64 + lr) * DIM + lk * 8;
    const __hip_bfloat16* Bbase = XN + (cb * 128 + wc * 64 + lr) * DIM + lk * 8;

    floatx4 acc[4][4];
    #pragma unroll
    for (int m = 0; m < 4; ++m)
        #pragma unroll
        for (int n = 0; n < 4; ++n)
            acc[m][n] = floatx4{0.f, 0.f, 0.f, 0.f};

    #pragma unroll
    for (int kk = 0; kk < 4; ++kk) {
        short8 a[4], b[4];
        #pragma unroll
        for (int m = 0; m < 4; ++m)
            a[m] = *reinterpret_cast<const short8*>(Abase + m * 16 * DIM + kk * 32);
        #pragma unroll
        for (int n = 0; n < 4; ++n)
            b[n] = *reinterpret_cast<const short8*>(Bbase + n * 16 * DIM + kk * 32);
        #pragma unroll
        for (int m = 0; m < 4; ++m)
            #pragma unroll
            for (int n = 0; n < 4; ++n)
                acc[m][n] = __builtin_amdgcn_mfma_f32_16x16x32_bf16(
                    a[m], b[n], acc[m][n], 0, 0, 0);
    }

    // ---- epilogue: exp once, accumulate row sums (and col sums off-diag) ----
    float rp[4][4];
    float cp[4] = {0.f, 0.f, 0.f, 0.f};
    #pragma unroll
    for (int m = 0; m < 4; ++m)
        #pragma unroll
        for (int r = 0; r < 4; ++r) rp[m][r] = 0.f;

    if (diag) {
        #pragma unroll
        for (int m = 0; m < 4; ++m)
            #pragma unroll
            for (int n = 0; n < 4; ++n)
                #pragma unroll
                for (int r = 0; r < 4; ++r) {
                    float e = __expf(acc[m][n][r]);
                    if (m == n && lr == lk * 4 + r) e = 0.f;  // exclude diagonal
                    rp[m][r] += e;
                }
    } else {
        #pragma unroll
        for (int m = 0; m < 4; ++m)
            #pragma unroll
            for (int n = 0; n < 4; ++n)
                #pragma unroll
                for (int r = 0; r < 4; ++r) {
                    const float e = __expf(acc[m][n][r]);
                    rp[m][r] += e;
                    cp[n] += e;
                }
    }

    const int rbase = rb * 128 + wr * 64;
    const int cbase = cb * 128 + wc * 64;

    // row sums: reduce across lr (16 lanes sharing a D row)
    #pragma unroll
    for (int m = 0; m < 4; ++m)
        #pragma unroll
        for (int r = 0; r < 4; ++r) {
            float v = rp[m][r];
            v += __shfl_xor(v, 1, 64);
            v += __shfl_xor(v, 2, 64);
            v += __shfl_xor(v, 4, 64);
            v += __shfl_xor(v, 8, 64);
            if (lr == 0) {
                const int row = rbase + m * 16 + lk * 4 + r;
                if (USEP)
                    ZP[(cb * 2 + wc) * B_ROWS + row] = v;
                else
                    atomicAdd(&ZP[row], v);
            }
        }

    // col sums (transpose contribution): reduce across lk groups
    if (!diag) {
        #pragma unroll
        for (int n = 0; n < 4; ++n) {
            float v = cp[n];
            v += __shfl_xor(v, 16, 64);
            v += __shfl_xor(v, 32, 64);
            if (lane < 16) {
                const int col = cbase + n * 16 + lr;
                if (USEP)
                    ZP[(rb * 2 + wr) * B_ROWS + col] = v;
                else
                    atomicAdd(&ZP[col], v);
            }
        }
    }
}

// ------------- final (P path): Z[r] = sum_t P[t][r]; loss reduce -------------
__global__ void kfinalP(const float* __restrict__ P, const float* __restrict__ pairT,
                        float* __restrict__ out) {
    const int r = blockIdx.x * 256 + threadIdx.x;
    float s = 0.f;
    if (r < B_ROWS - 2) {
        float z = 0.f;
        #pragma unroll 8
        for (int tt = 0; tt < 128; ++tt) z += P[tt * B_ROWS + r];
        s = logf(z);
    }
    if (r < NPAIR) s -= 2.f * pairT[r];
    #pragma unroll
    for (int m = 1; m < 64; m <<= 1) s += __shfl_xor(s, m, 64);
    __shared__ float red[4];
    const int wid = threadIdx.x >> 6;
    const int lane = threadIdx.x & 63;
    if (lane == 0) red[wid] = s;
    __syncthreads();
    if (threadIdx.x == 0) {
        float tsum = red[0] + red[1] + red[2] + red[3];
        atomicAdd(out, tsum / (float)B_ROWS);
    }
}

// ------------- final (Z fallback path) -------------
__global__ void kfinalZ(const float* __restrict__ Z, const float* __restrict__ pairT,
                        float* __restrict__ out) {
    float s = 0.f;
    for (int r = threadIdx.x; r < B_ROWS - 2; r += 1024) s += logf(Z[r]);
    for (int p = threadIdx.x; p < NPAIR; p += 1024) s -= 2.f * pairT[p];
    #pragma unroll
    for (int m = 1; m < 64; m <<= 1) s += __shfl_xor(s, m, 64);
    __shared__ float red[16];
    const int wid = threadIdx.x >> 6;
    const int lane = threadIdx.x & 63;
    if (lane == 0) red[wid] = s;
    __syncthreads();
    if (threadIdx.x == 0) {
        float t = 0.f;
        #pragma unroll
        for (int i = 0; i < 16; ++i) t += red[i];
        out[0] = t / (float)B_ROWS;
    }
}

extern "C" void kernel_launch(void* const* d_in, const int* in_sizes, int n_in,
                              void* d_out, int out_size, void* d_ws, size_t ws_size,
                              hipStream_t stream) {
    (void)in_sizes; (void)n_in; (void)out_size;
    const float* X = (const float*)d_in[0];
    float* out = (float*)d_out;
    char* ws = (char*)d_ws;

    float* Z = (float*)ws;                                   // 32 KB
    float* pairT = (float*)(ws + 32768);                     // 16 KB
    __hip_bfloat16* XN = (__hip_bfloat16*)(ws + 49152);      // 2 MB
    float* P = (float*)(ws + 49152 + 2097152);               // 4 MB
    const size_t need = 49152 + 2097152 + (size_t)128 * B_ROWS * 4;
    const bool useP = ws_size >= need;

    kprep<<<2048, 256, 0, stream>>>(X, XN, pairT, out);
    if (useP) {
        kgemm<true><<<2080, 256, 0, stream>>>(XN, P);
        kfinalP<<<32, 256, 0, stream>>>(P, pairT, out);
    } else {
        kzero<<<32, 256, 0, stream>>>(Z);
        kgemm<false><<<2080, 256, 0, stream>>>(XN, Z);
        kfinalZ<<<1, 1024, 0, stream>>>(Z, pairT, out);
    }
}

// Round 4
// 42.717 us; speedup vs baseline: 1.4027x; 1.4027x over previous
//
#include <hip/hip_runtime.h>
#include <hip/hip_bf16.h>

typedef __attribute__((ext_vector_type(8))) short short8;
typedef __attribute__((ext_vector_type(4))) float floatx4;

#define B_ROWS 8192
#define DIM 128
#define NPAIR 4095

// ---------------- zero Z (fallback path only) ----------------
__global__ void kzero(float* __restrict__ Z) {
    int i = blockIdx.x * 256 + threadIdx.x;
    if (i < B_ROWS) Z[i] = 0.f;
}

// ------------- fused prep: normalize rows -> bf16, pair dots, zero out -------------
__global__ void kprep(const float* __restrict__ X, __hip_bfloat16* __restrict__ XN,
                      float* __restrict__ pairT, float* __restrict__ out) {
    __shared__ float2 lds[4][64];
    const int wid = threadIdx.x >> 6;
    const int lane = threadIdx.x & 63;
    const int row = blockIdx.x * 4 + wid;

    const float2 v = *reinterpret_cast<const float2*>(X + row * DIM + lane * 2);
    float ss = v.x * v.x + v.y * v.y;
    #pragma unroll
    for (int m = 1; m < 64; m <<= 1) ss += __shfl_xor(ss, m, 64);
    const float rn = ss > 0.f ? rsqrtf(ss) : 0.f;
    const float2 nv = make_float2(v.x * rn, v.y * rn);

    *reinterpret_cast<__hip_bfloat162*>(XN + row * DIM + lane * 2) =
        __float22bfloat162_rn(nv);
    lds[wid][lane] = nv;
    __syncthreads();

    if ((wid & 1) == 0) {
        const int p = blockIdx.x * 2 + (wid >> 1);
        if (p < NPAIR) {
            const float2 a = lds[wid][lane];
            const float2 b = lds[wid + 1][lane];
            float d = a.x * b.x + a.y * b.y;
            #pragma unroll
            for (int m = 1; m < 64; m <<= 1) d += __shfl_xor(d, m, 64);
            if (lane == 0) pairT[p] = d;
        }
    }
    if (blockIdx.x == 0 && threadIdx.x == 0) out[0] = 0.f;
}

// ------------- main: row-panel persistent GEMM, A in registers, pipelined B -------------
// grid (8, 64): y = row panel rb (128 rows), x = col group g (8 consecutive 128-col tiles).
// 4 waves/block; wave owns 128 rows x 32 cols of each tile. Full matrix (no symmetry).
// rp accumulates row partial sums in registers across all 8 tiles.
template <bool USEP>
__global__ void __launch_bounds__(256, 2) kgemm(const __hip_bfloat16* __restrict__ XN,
                                                float* __restrict__ ZP) {
    const int wid = threadIdx.x >> 6;
    const int lane = threadIdx.x & 63;
    const int lr = lane & 15;
    const int lk = lane >> 4;
    const int rb = blockIdx.y;
    const int g = blockIdx.x;

    // ---- A panel fragments, loaded once: a[kk][m], rows rb*128 + m*16 + lr ----
    short8 a[4][8];
    const __hip_bfloat16* Abase = XN + (rb * 128 + lr) * DIM + lk * 8;
    #pragma unroll
    for (int m = 0; m < 8; ++m)
        #pragma unroll
        for (int kk = 0; kk < 4; ++kk)
            a[kk][m] = *reinterpret_cast<const short8*>(Abase + m * 16 * DIM + kk * 32);

    float rp[8][4];
    #pragma unroll
    for (int m = 0; m < 8; ++m)
        #pragma unroll
        for (int r = 0; r < 4; ++r) rp[m][r] = 0.f;

    // wave's column slice base within a tile: cols wid*32 + nh*16 + lr
    const __hip_bfloat16* Bcol = XN + (wid * 32 + lr) * DIM + lk * 8;

    short8 b0[4], b1[4];
    // prologue: issue loads for (tile 0, half 0)
    {
        const __hip_bfloat16* Bj = Bcol + (g * 8) * 128 * DIM;
        #pragma unroll
        for (int kk = 0; kk < 4; ++kk)
            b0[kk] = *reinterpret_cast<const short8*>(Bj + kk * 32);
    }

    for (int j = 0; j < 8; ++j) {
        const int cbj = g * 8 + j;
        const bool dtile = (cbj == rb);
        const __hip_bfloat16* Bj = Bcol + cbj * 128 * DIM;

        // issue half-1 loads (overlaps half-0 compute)
        #pragma unroll
        for (int kk = 0; kk < 4; ++kk)
            b1[kk] = *reinterpret_cast<const short8*>(Bj + 16 * DIM + kk * 32);

        // ---- half 0: cols wid*32 + lr ----
        floatx4 acc[8];
        #pragma unroll
        for (int m = 0; m < 8; ++m) acc[m] = floatx4{0.f, 0.f, 0.f, 0.f};
        #pragma unroll
        for (int kk = 0; kk < 4; ++kk)
            #pragma unroll
            for (int m = 0; m < 8; ++m)
                acc[m] = __builtin_amdgcn_mfma_f32_16x16x32_bf16(a[kk][m], b0[kk], acc[m], 0, 0, 0);

        if (dtile) {
            const int colid = wid * 32 + lr;
            #pragma unroll
            for (int m = 0; m < 8; ++m)
                #pragma unroll
                for (int r = 0; r < 4; ++r) {
                    float e = __expf(acc[m][r]);
                    if (m * 16 + lk * 4 + r == colid) e = 0.f;
                    rp[m][r] += e;
                }
        } else {
            #pragma unroll
            for (int m = 0; m < 8; ++m)
                #pragma unroll
                for (int r = 0; r < 4; ++r) rp[m][r] += __expf(acc[m][r]);
        }

        // issue half-0 loads for NEXT tile (overlaps half-1 compute)
        if (j < 7) {
            const __hip_bfloat16* Bn = Bcol + (cbj + 1) * 128 * DIM;
            #pragma unroll
            for (int kk = 0; kk < 4; ++kk)
                b0[kk] = *reinterpret_cast<const short8*>(Bn + kk * 32);
        }

        // ---- half 1: cols wid*32 + 16 + lr ----
        #pragma unroll
        for (int m = 0; m < 8; ++m) acc[m] = floatx4{0.f, 0.f, 0.f, 0.f};
        #pragma unroll
        for (int kk = 0; kk < 4; ++kk)
            #pragma unroll
            for (int m = 0; m < 8; ++m)
                acc[m] = __builtin_amdgcn_mfma_f32_16x16x32_bf16(a[kk][m], b1[kk], acc[m], 0, 0, 0);

        if (dtile) {
            const int colid = wid * 32 + 16 + lr;
            #pragma unroll
            for (int m = 0; m < 8; ++m)
                #pragma unroll
                for (int r = 0; r < 4; ++r) {
                    float e = __expf(acc[m][r]);
                    if (m * 16 + lk * 4 + r == colid) e = 0.f;
                    rp[m][r] += e;
                }
        } else {
            #pragma unroll
            for (int m = 0; m < 8; ++m)
                #pragma unroll
                for (int r = 0; r < 4; ++r) rp[m][r] += __expf(acc[m][r]);
        }
    }

    // ---- per-block row sums: reduce over lr, store slot (g*4 + wid) ----
    #pragma unroll
    for (int m = 0; m < 8; ++m)
        #pragma unroll
        for (int r = 0; r < 4; ++r) {
            float v = rp[m][r];
            v += __shfl_xor(v, 1, 64);
            v += __shfl_xor(v, 2, 64);
            v += __shfl_xor(v, 4, 64);
            v += __shfl_xor(v, 8, 64);
            if (lr == 0) {
                const int row = rb * 128 + m * 16 + lk * 4 + r;
                if (USEP)
                    ZP[(g * 4 + wid) * B_ROWS + row] = v;
                else
                    atomicAdd(&ZP[row], v);
            }
        }
}

// ------------- final (P path): Z[r] = sum_{32 slots} P[t][r]; loss reduce -------------
__global__ void kfinalP(const float* __restrict__ P, const float* __restrict__ pairT,
                        float* __restrict__ out) {
    const int r = blockIdx.x * 256 + threadIdx.x;
    float s = 0.f;
    if (r < B_ROWS - 2) {
        float z = 0.f;
        #pragma unroll
        for (int tt = 0; tt < 32; ++tt) z += P[tt * B_ROWS + r];
        s = logf(z);
    }
    if (r < NPAIR) s -= 2.f * pairT[r];
    #pragma unroll
    for (int m = 1; m < 64; m <<= 1) s += __shfl_xor(s, m, 64);
    __shared__ float red[4];
    const int wid = threadIdx.x >> 6;
    const int lane = threadIdx.x & 63;
    if (lane == 0) red[wid] = s;
    __syncthreads();
    if (threadIdx.x == 0) {
        float tsum = red[0] + red[1] + red[2] + red[3];
        atomicAdd(out, tsum / (float)B_ROWS);
    }
}

// ------------- final (Z fallback path) -------------
__global__ void kfinalZ(const float* __restrict__ Z, const float* __restrict__ pairT,
                        float* __restrict__ out) {
    float s = 0.f;
    for (int r = threadIdx.x; r < B_ROWS - 2; r += 1024) s += logf(Z[r]);
    for (int p = threadIdx.x; p < NPAIR; p += 1024) s -= 2.f * pairT[p];
    #pragma unroll
    for (int m = 1; m < 64; m <<= 1) s += __shfl_xor(s, m, 64);
    __shared__ float red[16];
    const int wid = threadIdx.x >> 6;
    const int lane = threadIdx.x & 63;
    if (lane == 0) red[wid] = s;
    __syncthreads();
    if (threadIdx.x == 0) {
        float t = 0.f;
        #pragma unroll
        for (int i = 0; i < 16; ++i) t += red[i];
        out[0] = t / (float)B_ROWS;
    }
}

extern "C" void kernel_launch(void* const* d_in, const int* in_sizes, int n_in,
                              void* d_out, int out_size, void* d_ws, size_t ws_size,
                              hipStream_t stream) {
    (void)in_sizes; (void)n_in; (void)out_size;
    const float* X = (const float*)d_in[0];
    float* out = (float*)d_out;
    char* ws = (char*)d_ws;

    float* Z = (float*)ws;                                   // 32 KB
    float* pairT = (float*)(ws + 32768);                     // 16 KB
    __hip_bfloat16* XN = (__hip_bfloat16*)(ws + 49152);      // 2 MB
    float* P = (float*)(ws + 49152 + 2097152);               // 1 MB (32 x 8192 f32)
    const size_t need = 49152 + 2097152 + (size_t)32 * B_ROWS * 4;
    const bool useP = ws_size >= need;

    kprep<<<2048, 256, 0, stream>>>(X, XN, pairT, out);
    if (useP) {
        kgemm<true><<<dim3(8, 64), 256, 0, stream>>>(XN, P);
        kfinalP<<<32, 256, 0, stream>>>(P, pairT, out);
    } else {
        kzero<<<32, 256, 0, stream>>>(Z);
        kgemm<false><<<dim3(8, 64), 256, 0, stream>>>(XN, Z);
        kfinalZ<<<1, 1024, 0, stream>>>(Z, pairT, out);
    }
}